// Round 1
// baseline (728.328 us; speedup 1.0000x reference)
//
#include <hip/hip_runtime.h>
#include <hip/hip_bf16.h>
#include <stdint.h>

#define NTOT 131072
#define NSEG 16
#define EPSV 1e-5f

typedef __attribute__((ext_vector_type(8))) short bf16x8;
typedef __attribute__((ext_vector_type(4))) float f32x4;

struct Args {
  const float* x; const int* npts;
  const float *W1,*b1,*g1,*be1,*m1,*v1;
  const float *W2,*b2,*g2,*be2,*m2,*v2;
  const float *W3,*b3,*g3,*be3,*m3,*v3;
  const float *W4,*b4,*g4,*be4,*m4,*v4;
  int* offs;
  float *a1,*c1,*a2,*c2,*a3,*c3,*a4,*c4;
  unsigned int *gkeys,*vkeys;
  unsigned short *w2b;
  unsigned short *w3p;     // [2 cgrp][8 ks32][4 kgrel][256 cout][8]  (f-part of W3, k=256..512)
  unsigned short *w4p;     // [4 cgrp][16 ks32][4 kgrel][256 cout][8]
  unsigned short *fbufp;   // [512 ptblk][32 kg][256 pt][8]
  unsigned short *h3p;     // [512 ptblk][64 kg][256 pt][8]
  float* cseg;             // [16][512] = W3[:, :256] @ gs(seg)
  float* out;
};

__device__ inline unsigned int f2key(float f){ unsigned u=__float_as_uint(f); return (u&0x80000000u)? ~u : (u|0x80000000u); }
__device__ inline float key2f(unsigned k){ unsigned u=(k&0x80000000u)? (k^0x80000000u) : ~k; return __uint_as_float(u); }
__device__ inline unsigned short f2bf(float f){ __hip_bfloat16 h=__float2bfloat16(f); return *(unsigned short*)&h; }

__device__ inline void gl16(const void* g, void* l){
  __builtin_amdgcn_global_load_lds((const __attribute__((address_space(1))) unsigned int*)g,
                                   (__attribute__((address_space(3))) unsigned int*)l, 16, 0, 0);
}

// ---------------- setup ----------------
__global__ void k_setup(Args A){
  int tid = threadIdx.x;
  if (tid==0){ int s=0; A.offs[0]=0; for (int i=0;i<NSEG;i++){ s+=A.npts[i]; A.offs[i+1]=s; } }
  for (int c=tid;c<128;c+=256){ float a=A.g1[c]*rsqrtf(A.v1[c]+EPSV); A.a1[c]=a; A.c1[c]=A.be1[c]+a*(A.b1[c]-A.m1[c]); }
  for (int c=tid;c<256;c+=256){ float a=A.g2[c]*rsqrtf(A.v2[c]+EPSV); A.a2[c]=a; A.c2[c]=A.be2[c]+a*(A.b2[c]-A.m2[c]); }
  for (int c=tid;c<512;c+=256){ float a=A.g3[c]*rsqrtf(A.v3[c]+EPSV); A.a3[c]=a; A.c3[c]=A.be3[c]+a*(A.b3[c]-A.m3[c]); }
  for (int c=tid;c<1024;c+=256){ float a=A.g4[c]*rsqrtf(A.v4[c]+EPSV); A.a4[c]=a; A.c4[c]=A.be4[c]+a*(A.b4[c]-A.m4[c]); }
  for (int i=tid;i<NSEG*256;i+=256)  A.gkeys[i]=0u;
  for (int i=tid;i<NSEG*1024;i+=256) A.vkeys[i]=0u;
}

// ---------------- weights fp32 -> bf16 (w2b plain, w3p/w4p stage-chunk-packed) ----------------
// w3p entry o: o = cg<<16 | ks<<13 | kgrel<<11 | cout<<3 | j  -> W3[(cg*256+cout)*512 + 256 + ks*32+kgrel*8+j]
// w4p entry o: o = cg<<17 | ks<<13 | kgrel<<11 | cout<<3 | j  -> W4[(cg*256+cout)*512 + ks*32+kgrel*8+j]
__global__ void k_conv(Args A){
  const int n1=256*128;        // 32768
  const int n2=131072;
  const int n3=524288;
  for (int i = blockIdx.x*256+threadIdx.x; i < n1+n2+n3; i += gridDim.x*256){
    if (i<n1) A.w2b[i]=f2bf(A.W2[i]);
    else if (i<n1+n2){
      int o=i-n1; int j=o&7, cout=(o>>3)&255, kgrel=(o>>11)&3, ks=(o>>13)&7, cg=(o>>16)&1;
      A.w3p[o]=f2bf(A.W3[(size_t)(cg*256+cout)*512 + 256 + ks*32 + kgrel*8 + j]);
    } else {
      int o=i-n1-n2; int j=o&7, cout=(o>>3)&255, kgrel=(o>>11)&3, ks=(o>>13)&15, cg=(o>>17)&3;
      A.w4p[o]=f2bf(A.W4[(size_t)(cg*256+cout)*512 + ks*32 + kgrel*8 + j]);
    }
  }
}

// ---------------- L1 (VALU) + L2 (MFMA) + BN -> fbufp packed + gkeys ----------------
__global__ __launch_bounds__(256) void k_l12(Args A){
  __shared__ float w1s[384], a1s[128], c1s[128], a2s[256], c2s[256];
  __shared__ float xs[3][64];
  __shared__ int offs_s[NSEG+1], segp[64];
  __shared__ unsigned short hs[16*64*8];
  int tid=threadIdx.x, pt0=blockIdx.x*64;
  for (int i=tid;i<384;i+=256) w1s[i]=A.W1[i];
  if (tid<128){ a1s[tid]=A.a1[tid]; c1s[tid]=A.c1[tid]; }
  a2s[tid]=A.a2[tid]; c2s[tid]=A.c2[tid];
  if (tid<=NSEG) offs_s[tid]=A.offs[tid];
  if (tid<64){ xs[0][tid]=A.x[pt0+tid]; xs[1][tid]=A.x[NTOT+pt0+tid]; xs[2][tid]=A.x[2*NTOT+pt0+tid]; }
  __syncthreads();
  if (tid<64){ int gp=pt0+tid, s=0; while (gp>=offs_s[s+1]) s++; segp[tid]=s; }
  for (int pair=tid; pair<1024; pair+=256){
    int pt=pair&63, kc=pair>>6;
    float x0=xs[0][pt], x1=xs[1][pt], x2=xs[2][pt];
    unsigned short us[8];
    #pragma unroll
    for (int j=0;j<8;j++){
      int cin=kc*8+j;
      float v = fmaf(w1s[cin*3],x0, fmaf(w1s[cin*3+1],x1, w1s[cin*3+2]*x2));
      v = fmaxf(fmaf(a1s[cin],v,c1s[cin]), 0.f);
      us[j]=f2bf(v);
    }
    uint4 pk;
    pk.x=(unsigned)us[0]|((unsigned)us[1]<<16); pk.y=(unsigned)us[2]|((unsigned)us[3]<<16);
    pk.z=(unsigned)us[4]|((unsigned)us[5]<<16); pk.w=(unsigned)us[6]|((unsigned)us[7]<<16);
    *(uint4*)(&hs[(kc*64+pt)*8]) = pk;
  }
  __syncthreads();
  int lane=tid&63, wv=tid>>6, quad=lane>>4, l16=lane&15;
  int m0=wv*64;
  f32x4 acc[4][4];
  for (int a=0;a<4;a++)
    for (int b=0;b<4;b++)
      acc[a][b]=(f32x4){0.f,0.f,0.f,0.f};
  #pragma unroll
  for (int ks=0; ks<4; ++ks){
    bf16x8 bfr[4];
    #pragma unroll
    for (int nt=0; nt<4; ++nt) bfr[nt]=*(bf16x8*)(&hs[((ks*4+quad)*64 + nt*16 + l16)*8]);
    #pragma unroll
    for (int mt=0; mt<4; ++mt){
      bf16x8 afr = *(const bf16x8*)(&A.w2b[(m0+mt*16+l16)*128 + ks*32 + quad*8]);
      #pragma unroll
      for (int nt=0; nt<4; ++nt)
        acc[mt][nt]=__builtin_amdgcn_mfma_f32_16x16x32_bf16(afr, bfr[nt], acc[mt][nt], 0,0,0);
    }
  }
  bool uni = (segp[0]==segp[63]); int seg0=segp[0];
  size_t tb = (size_t)(blockIdx.x>>2)*65536;   // ptblk base in fbufp entries
  int prelb = (blockIdx.x&3)*64;
  #pragma unroll
  for (int mt=0;mt<4;++mt){
    int cout0=m0+mt*16+quad*4;
    int kg=cout0>>3, sub=cout0&7;
    float fv[4][4];
    #pragma unroll
    for (int nt=0;nt<4;++nt)
      #pragma unroll
      for (int r=0;r<4;++r)
        fv[nt][r]=fmaf(a2s[cout0+r], acc[mt][nt][r], c2s[cout0+r]);
    #pragma unroll
    for (int nt=0;nt<4;++nt){
      int ptl=nt*16+l16;
      uint2 pk;
      pk.x=(unsigned)f2bf(fv[nt][0])|((unsigned)f2bf(fv[nt][1])<<16);
      pk.y=(unsigned)f2bf(fv[nt][2])|((unsigned)f2bf(fv[nt][3])<<16);
      *(uint2*)&A.fbufp[tb + (size_t)((kg*256 + prelb + ptl)*8 + sub)] = pk;
    }
    #pragma unroll
    for (int r=0;r<4;++r){
      if (uni){
        float mv=fmaxf(fmaxf(fv[0][r],fv[1][r]),fmaxf(fv[2][r],fv[3][r]));
        #pragma unroll
        for (int off=8;off>=1;off>>=1) mv=fmaxf(mv, __shfl_xor(mv,off));
        if (l16==0) atomicMax(&A.gkeys[seg0*256+cout0+r], f2key(mv));
      } else {
        #pragma unroll
        for (int nt=0;nt<4;++nt)
          atomicMax(&A.gkeys[segp[nt*16+l16]*256+cout0+r], f2key(fv[nt][r]));
      }
    }
  }
}

// ---------------- cseg[seg][cout] = W3[:, :256] @ gs(seg) ----------------
__global__ void k_cseg(Args A){
  int seg = blockIdx.x>>1; int cout = (blockIdx.x&1)*256 + threadIdx.x;
  __shared__ float gs[256];
  gs[threadIdx.x] = key2f(A.gkeys[seg*256+threadIdx.x]);
  __syncthreads();
  const float* wrow = A.W3 + (size_t)cout*512;
  float s=0.f;
  #pragma unroll 8
  for (int k=0;k<256;k++) s = fmaf(wrow[k], gs[k], s);
  A.cseg[seg*512+cout]=s;
}

// ---------------- L3: 256x256 tile, both operands LDS-staged via gl16, counted-vmcnt pipeline ----------------
// 1024 blocks x 512 thr. Block = 256 couts (cgrp of 2) x 256 pts (one ptblk). K=256 -> NS=8 stages of BK=32.
// 4 LDS buffers, 2-stage lookahead, vmcnt(8) steady state (never drained), raw s_barrier.
__global__ __launch_bounds__(512,2) void k_l3(Args A){
  __shared__ unsigned short sA[4][8192];   // [4 kgrel][256 cout][8] per buffer, 16 KB
  __shared__ unsigned short sB[4][8192];   // [4 kgrel][256 pt][8]
  __shared__ int offs_s[NSEG+1];
  const int NS=8;
  int bid=blockIdx.x, xcd=bid&7, j=bid>>3;
  int cgrp=j&1, ptblk=xcd*64+(j>>1);
  int tid=threadIdx.x, lane=tid&63, wv=tid>>6, quad=lane>>4, l16=lane&15;
  int mq=wv&1, tq=wv>>1;
  const char* wbase0 = (const char*)A.w3p + (size_t)cgrp*131072;    // 65536 entries * 2B
  const char* bbase0 = (const char*)A.fbufp + (size_t)ptblk*131072; // 65536 entries * 2B
  if (tid<=NSEG) offs_s[tid]=A.offs[tid];

  auto stage=[&](int buf, int s){
    char* lA=(char*)&sA[buf][0];
    char* lB=(char*)&sB[buf][0];
    if (wv<4){
      const char* src = wbase0 + (size_t)s*16384;
      #pragma unroll
      for (int i=0;i<4;++i){ int c=wv*4+i; gl16(src + c*1024 + lane*16, lA + c*1024); }
    } else {
      const char* src = bbase0 + (size_t)s*16384;
      #pragma unroll
      for (int i=0;i<4;++i){ int c=(wv-4)*4+i; gl16(src + c*1024 + lane*16, lB + c*1024); }
    }
  };

  f32x4 acc[8][4];
  for (int a=0;a<8;a++)
    for (int b=0;b<4;b++)
      acc[a][b]=(f32x4){0.f,0.f,0.f,0.f};

  stage(0,0); stage(1,1);
  asm volatile("s_waitcnt lgkmcnt(0)" ::: "memory");
  asm volatile("s_waitcnt vmcnt(4)" ::: "memory");
  __builtin_amdgcn_s_barrier();
  __builtin_amdgcn_sched_barrier(0);

  #pragma unroll
  for (int s=0;s<NS;++s){
    int cur=s&3;
    if (s+2<NS) stage((s+2)&3, s+2);
    if (s+2<NS)      asm volatile("s_waitcnt vmcnt(8)" ::: "memory");
    else if (s+1<NS) asm volatile("s_waitcnt vmcnt(4)" ::: "memory");
    else             asm volatile("s_waitcnt vmcnt(0)" ::: "memory");
    __builtin_amdgcn_s_barrier();
    __builtin_amdgcn_sched_barrier(0);
    bf16x8 afr[8], bb[4];
    #pragma unroll
    for (int mt=0;mt<8;++mt) afr[mt]=*(const bf16x8*)(&sA[cur][(quad*256 + mq*128 + mt*16 + l16)*8]);
    #pragma unroll
    for (int nt=0;nt<4;++nt) bb[nt]=*(const bf16x8*)(&sB[cur][(quad*256 + tq*64 + nt*16 + l16)*8]);
    __builtin_amdgcn_s_setprio(1);
    #pragma unroll
    for (int mt=0;mt<8;++mt)
      #pragma unroll
      for (int nt=0;nt<4;++nt)
        acc[mt][nt]=__builtin_amdgcn_mfma_f32_16x16x32_bf16(afr[mt], bb[nt], acc[mt][nt], 0,0,0);
    __builtin_amdgcn_s_setprio(0);
  }

  // epilogue: BN + ReLU + cseg add, pack to h3p
  int pt0 = ptblk*256 + tq*64;
  int sBeg=0; while (pt0 >= offs_s[sBeg+1]) sBeg++;
  int sEnd=sBeg; while (pt0+63 >= offs_s[sEnd+1]) sEnd++;
  bool uni=(sBeg==sEnd);
  int segl[4];
  if (!uni){
    #pragma unroll
    for (int nt=0;nt<4;++nt){ int gp=pt0+nt*16+l16, ss=sBeg; while (gp>=offs_s[ss+1]) ss++; segl[nt]=ss; }
  }
  size_t hb = (size_t)ptblk*131072;
  #pragma unroll
  for (int mt=0;mt<8;++mt){
    int cout0=cgrp*256 + mq*128 + mt*16 + quad*4;
    int kg=cout0>>3, sub=cout0&7;
    float sa[4],sc[4],csr[4];
    #pragma unroll
    for (int r=0;r<4;++r){ sa[r]=A.a3[cout0+r]; sc[r]=A.c3[cout0+r]; }
    if (uni){
      #pragma unroll
      for (int r=0;r<4;++r) csr[r]=A.cseg[sBeg*512+cout0+r];
    }
    #pragma unroll
    for (int nt=0;nt<4;++nt){
      int prel=tq*64+nt*16+l16;
      unsigned short us[4];
      #pragma unroll
      for (int r=0;r<4;++r){
        float cv = uni? csr[r] : A.cseg[segl[nt]*512+cout0+r];
        float hv = fmaxf(fmaf(sa[r], acc[mt][nt][r]+cv, sc[r]), 0.f);
        us[r]=f2bf(hv);
      }
      uint2 pk;
      pk.x=(unsigned)us[0]|((unsigned)us[1]<<16);
      pk.y=(unsigned)us[2]|((unsigned)us[3]<<16);
      *(uint2*)&A.h3p[hb + (size_t)((kg*256+prel)*8+sub)] = pk;
    }
  }
}

// ---------------- L4: same pipeline, K=512 -> NS=16, fused segmax ----------------
// 2048 blocks x 512 thr. Block = 256 couts (cgrp of 4) x 256 pts. XCD swizzle keeps 4 cgrps of a ptblk co-resident.
__global__ __launch_bounds__(512,2) void k_l4(Args A){
  __shared__ unsigned short sA[4][8192];
  __shared__ unsigned short sB[4][8192];
  __shared__ int offs_s[NSEG+1];
  const int NS=16;
  int bid=blockIdx.x, xcd=bid&7, j=bid>>3;
  int cgrp=j&3, ptblk=xcd*64+(j>>2);
  int tid=threadIdx.x, lane=tid&63, wv=tid>>6, quad=lane>>4, l16=lane&15;
  int mq=wv&1, tq=wv>>1;
  const char* wbase0 = (const char*)A.w4p + (size_t)cgrp*262144;   // 131072 entries * 2B
  const char* bbase0 = (const char*)A.h3p + (size_t)ptblk*262144;  // 131072 entries * 2B
  if (tid<=NSEG) offs_s[tid]=A.offs[tid];

  auto stage=[&](int buf, int s){
    char* lA=(char*)&sA[buf][0];
    char* lB=(char*)&sB[buf][0];
    if (wv<4){
      const char* src = wbase0 + (size_t)s*16384;
      #pragma unroll
      for (int i=0;i<4;++i){ int c=wv*4+i; gl16(src + c*1024 + lane*16, lA + c*1024); }
    } else {
      const char* src = bbase0 + (size_t)s*16384;
      #pragma unroll
      for (int i=0;i<4;++i){ int c=(wv-4)*4+i; gl16(src + c*1024 + lane*16, lB + c*1024); }
    }
  };

  f32x4 acc[8][4];
  for (int a=0;a<8;a++)
    for (int b=0;b<4;b++)
      acc[a][b]=(f32x4){0.f,0.f,0.f,0.f};

  stage(0,0); stage(1,1);
  asm volatile("s_waitcnt lgkmcnt(0)" ::: "memory");
  asm volatile("s_waitcnt vmcnt(4)" ::: "memory");
  __builtin_amdgcn_s_barrier();
  __builtin_amdgcn_sched_barrier(0);

  #pragma unroll
  for (int s=0;s<NS;++s){
    int cur=s&3;
    if (s+2<NS) stage((s+2)&3, s+2);
    if (s+2<NS)      asm volatile("s_waitcnt vmcnt(8)" ::: "memory");
    else if (s+1<NS) asm volatile("s_waitcnt vmcnt(4)" ::: "memory");
    else             asm volatile("s_waitcnt vmcnt(0)" ::: "memory");
    __builtin_amdgcn_s_barrier();
    __builtin_amdgcn_sched_barrier(0);
    bf16x8 afr[8], bb[4];
    #pragma unroll
    for (int mt=0;mt<8;++mt) afr[mt]=*(const bf16x8*)(&sA[cur][(quad*256 + mq*128 + mt*16 + l16)*8]);
    #pragma unroll
    for (int nt=0;nt<4;++nt) bb[nt]=*(const bf16x8*)(&sB[cur][(quad*256 + tq*64 + nt*16 + l16)*8]);
    __builtin_amdgcn_s_setprio(1);
    #pragma unroll
    for (int mt=0;mt<8;++mt)
      #pragma unroll
      for (int nt=0;nt<4;++nt)
        acc[mt][nt]=__builtin_amdgcn_mfma_f32_16x16x32_bf16(afr[mt], bb[nt], acc[mt][nt], 0,0,0);
    __builtin_amdgcn_s_setprio(0);
  }

  // epilogue: BN + fused segmax
  int pt0 = ptblk*256 + tq*64;
  int sBeg=0; while (pt0 >= offs_s[sBeg+1]) sBeg++;
  int sEnd=sBeg; while (pt0+63 >= offs_s[sEnd+1]) sEnd++;
  bool uni=(sBeg==sEnd);
  int segl[4];
  if (!uni){
    #pragma unroll
    for (int nt=0;nt<4;++nt){ int gp=pt0+nt*16+l16, ss=sBeg; while (gp>=offs_s[ss+1]) ss++; segl[nt]=ss; }
  }
  #pragma unroll
  for (int mt=0;mt<8;++mt){
    int cout0=cgrp*256 + mq*128 + mt*16 + quad*4;
    #pragma unroll
    for (int r=0;r<4;++r){
      int cout=cout0+r;
      float sa=A.a4[cout], sc=A.c4[cout];
      float mv=-3.4e38f;
      #pragma unroll
      for (int nt=0;nt<4;++nt){
        float fv=fmaf(sa, acc[mt][nt][r], sc);
        if (uni) mv=fmaxf(mv,fv);
        else atomicMax(&A.vkeys[segl[nt]*1024+cout], f2key(fv));
      }
      if (uni){
        #pragma unroll
        for (int off=8;off>=1;off>>=1) mv=fmaxf(mv, __shfl_xor(mv,off));
        if (l16==0) atomicMax(&A.vkeys[sBeg*1024+cout], f2key(mv));
      }
    }
  }
}

// ---------------- decode ----------------
__global__ void k_final(Args A){
  int i=blockIdx.x*256+threadIdx.x;
  if (i<NSEG*1024) A.out[i]=key2f(A.vkeys[i]);
}

extern "C" void kernel_launch(void* const* d_in, const int* in_sizes, int n_in,
                              void* d_out, int out_size, void* d_ws, size_t ws_size,
                              hipStream_t stream){
  Args A;
  A.x  =(const float*)d_in[0];  A.npts=(const int*)d_in[1];
  A.W1 =(const float*)d_in[2];  A.b1 =(const float*)d_in[3];
  A.g1 =(const float*)d_in[4];  A.be1=(const float*)d_in[5];
  A.m1 =(const float*)d_in[6];  A.v1 =(const float*)d_in[7];
  A.W2 =(const float*)d_in[8];  A.b2 =(const float*)d_in[9];
  A.g2 =(const float*)d_in[10]; A.be2=(const float*)d_in[11];
  A.m2 =(const float*)d_in[12]; A.v2 =(const float*)d_in[13];
  A.W3 =(const float*)d_in[14]; A.b3 =(const float*)d_in[15];
  A.g3 =(const float*)d_in[16]; A.be3=(const float*)d_in[17];
  A.m3 =(const float*)d_in[18]; A.v3 =(const float*)d_in[19];
  A.W4 =(const float*)d_in[20]; A.b4 =(const float*)d_in[21];
  A.g4 =(const float*)d_in[22]; A.be4=(const float*)d_in[23];
  A.m4 =(const float*)d_in[24]; A.v4 =(const float*)d_in[25];

  char* w=(char*)d_ws;
  auto alloc=[&](size_t b)->void*{ void* p=(void*)w; w += (b+255)&~(size_t)255; return p; };
  A.offs =(int*)alloc((NSEG+1)*4);
  A.a1=(float*)alloc(128*4);  A.c1=(float*)alloc(128*4);
  A.a2=(float*)alloc(256*4);  A.c2=(float*)alloc(256*4);
  A.a3=(float*)alloc(512*4);  A.c3=(float*)alloc(512*4);
  A.a4=(float*)alloc(1024*4); A.c4=(float*)alloc(1024*4);
  A.gkeys=(unsigned int*)alloc(NSEG*256*4);
  A.vkeys=(unsigned int*)alloc(NSEG*1024*4);
  A.cseg =(float*)alloc(NSEG*512*4);
  A.w2b=(unsigned short*)alloc(256*128*2);
  A.w3p=(unsigned short*)alloc(131072*2);
  A.w4p=(unsigned short*)alloc(524288*2);
  A.fbufp=(unsigned short*)alloc((size_t)512*65536*2);   // 64 MB
  A.h3p  =(unsigned short*)alloc((size_t)512*131072*2);  // 128 MB
  A.out=(float*)d_out;

  k_setup<<<dim3(1),dim3(256),0,stream>>>(A);
  k_conv <<<dim3(2688),dim3(256),0,stream>>>(A);
  k_l12  <<<dim3(NTOT/64),dim3(256),0,stream>>>(A);
  k_cseg <<<dim3(32),dim3(256),0,stream>>>(A);
  k_l3   <<<dim3(1024),dim3(512),0,stream>>>(A);
  k_l4   <<<dim3(2048),dim3(512),0,stream>>>(A);
  k_final<<<dim3(64),dim3(256),0,stream>>>(A);
}

// Round 2
// 604.217 us; speedup vs baseline: 1.2054x; 1.2054x over previous
//
#include <hip/hip_runtime.h>
#include <hip/hip_bf16.h>
#include <stdint.h>

#define NTOT 131072
#define NSEG 16
#define EPSV 1e-5f

typedef __attribute__((ext_vector_type(8))) short bf16x8;
typedef __attribute__((ext_vector_type(4))) float f32x4;

struct Args {
  const float* x; const int* npts;
  const float *W1,*b1,*g1,*be1,*m1,*v1;
  const float *W2,*b2,*g2,*be2,*m2,*v2;
  const float *W3,*b3,*g3,*be3,*m3,*v3;
  const float *W4,*b4,*g4,*be4,*m4,*v4;
  int* offs;
  float *a1,*c1,*a2,*c2,*a3,*c3,*a4,*c4;
  unsigned int *gkeys,*vkeys;
  unsigned short *w2b;
  unsigned short *w3p;     // [4 mtile][32 kgg][128 cout_rel][8]   (f-part of W3, k=256..512)
  unsigned short *w4p;     // [8 mtile][64 kgg][128 cout_rel][8]
  unsigned short *fbufp;   // [1024 ntile][32 kgg][128 pt_rel][8]  (f acts, 256 ch)
  unsigned short *h3p;     // [1024 ntile][64 kgg][128 pt_rel][8]  (h3 acts, 512 ch)
  float* cseg;             // [16][512] = W3[:, :256] @ gs(seg)
  float* out;
};

__device__ inline unsigned int f2key(float f){ unsigned u=__float_as_uint(f); return (u&0x80000000u)? ~u : (u|0x80000000u); }
__device__ inline float key2f(unsigned k){ unsigned u=(k&0x80000000u)? (k^0x80000000u) : ~k; return __uint_as_float(u); }
__device__ inline unsigned short f2bf(float f){ __hip_bfloat16 h=__float2bfloat16(f); return *(unsigned short*)&h; }

__device__ inline void gl16(const void* g, void* l){
  __builtin_amdgcn_global_load_lds((const __attribute__((address_space(1))) unsigned int*)g,
                                   (__attribute__((address_space(3))) unsigned int*)l, 16, 0, 0);
}

// ---------------- setup ----------------
__global__ void k_setup(Args A){
  int tid = threadIdx.x;
  if (tid==0){ int s=0; A.offs[0]=0; for (int i=0;i<NSEG;i++){ s+=A.npts[i]; A.offs[i+1]=s; } }
  for (int c=tid;c<128;c+=256){ float a=A.g1[c]*rsqrtf(A.v1[c]+EPSV); A.a1[c]=a; A.c1[c]=A.be1[c]+a*(A.b1[c]-A.m1[c]); }
  for (int c=tid;c<256;c+=256){ float a=A.g2[c]*rsqrtf(A.v2[c]+EPSV); A.a2[c]=a; A.c2[c]=A.be2[c]+a*(A.b2[c]-A.m2[c]); }
  for (int c=tid;c<512;c+=256){ float a=A.g3[c]*rsqrtf(A.v3[c]+EPSV); A.a3[c]=a; A.c3[c]=A.be3[c]+a*(A.b3[c]-A.m3[c]); }
  for (int c=tid;c<1024;c+=256){ float a=A.g4[c]*rsqrtf(A.v4[c]+EPSV); A.a4[c]=a; A.c4[c]=A.be4[c]+a*(A.b4[c]-A.m4[c]); }
  for (int i=tid;i<NSEG*256;i+=256)  A.gkeys[i]=0u;
  for (int i=tid;i<NSEG*1024;i+=256) A.vkeys[i]=0u;
}

// ---------------- weights fp32 -> bf16, tile-packed for gl16 staging ----------------
// w3p[o]: o = mtile<<15 | kgg<<10 | cout_rel<<3 | j  -> W3[(mtile*128+cout_rel)*512 + 256 + kgg*8 + j]
// w4p[o]: o = mtile<<16 | kgg<<10 | cout_rel<<3 | j  -> W4[(mtile*128+cout_rel)*512 + kgg*8 + j]
__global__ void k_conv(Args A){
  const int n1=256*128;        // 32768
  const int n2=131072;
  const int n3=524288;
  for (int i = blockIdx.x*256+threadIdx.x; i < n1+n2+n3; i += gridDim.x*256){
    if (i<n1) A.w2b[i]=f2bf(A.W2[i]);
    else if (i<n1+n2){
      int o=i-n1; int j=o&7, cr=(o>>3)&127, kgg=(o>>10)&31, mt=o>>15;
      A.w3p[o]=f2bf(A.W3[(size_t)(mt*128+cr)*512 + 256 + kgg*8 + j]);
    } else {
      int o=i-n1-n2; int j=o&7, cr=(o>>3)&127, kgg=(o>>10)&63, mt=o>>16;
      A.w4p[o]=f2bf(A.W4[(size_t)(mt*128+cr)*512 + kgg*8 + j]);
    }
  }
}

// ---------------- L1 (VALU) + L2 (MFMA) + BN -> fbufp packed + gkeys ----------------
__global__ __launch_bounds__(256) void k_l12(Args A){
  __shared__ float w1s[384], a1s[128], c1s[128], a2s[256], c2s[256];
  __shared__ float xs[3][64];
  __shared__ int offs_s[NSEG+1], segp[64];
  __shared__ unsigned short hs[16*64*8];
  int tid=threadIdx.x, pt0=blockIdx.x*64;
  for (int i=tid;i<384;i+=256) w1s[i]=A.W1[i];
  if (tid<128){ a1s[tid]=A.a1[tid]; c1s[tid]=A.c1[tid]; }
  a2s[tid]=A.a2[tid]; c2s[tid]=A.c2[tid];
  if (tid<=NSEG) offs_s[tid]=A.offs[tid];
  if (tid<64){ xs[0][tid]=A.x[pt0+tid]; xs[1][tid]=A.x[NTOT+pt0+tid]; xs[2][tid]=A.x[2*NTOT+pt0+tid]; }
  __syncthreads();
  if (tid<64){ int gp=pt0+tid, s=0; while (gp>=offs_s[s+1]) s++; segp[tid]=s; }
  for (int pair=tid; pair<1024; pair+=256){
    int pt=pair&63, kc=pair>>6;
    float x0=xs[0][pt], x1=xs[1][pt], x2=xs[2][pt];
    unsigned short us[8];
    #pragma unroll
    for (int j=0;j<8;j++){
      int cin=kc*8+j;
      float v = fmaf(w1s[cin*3],x0, fmaf(w1s[cin*3+1],x1, w1s[cin*3+2]*x2));
      v = fmaxf(fmaf(a1s[cin],v,c1s[cin]), 0.f);
      us[j]=f2bf(v);
    }
    uint4 pk;
    pk.x=(unsigned)us[0]|((unsigned)us[1]<<16); pk.y=(unsigned)us[2]|((unsigned)us[3]<<16);
    pk.z=(unsigned)us[4]|((unsigned)us[5]<<16); pk.w=(unsigned)us[6]|((unsigned)us[7]<<16);
    *(uint4*)(&hs[(kc*64+pt)*8]) = pk;
  }
  __syncthreads();
  int lane=tid&63, wv=tid>>6, quad=lane>>4, l16=lane&15;
  int m0=wv*64;
  f32x4 acc[4][4];
  for (int a=0;a<4;a++)
    for (int b=0;b<4;b++)
      acc[a][b]=(f32x4){0.f,0.f,0.f,0.f};
  #pragma unroll
  for (int ks=0; ks<4; ++ks){
    bf16x8 bfr[4];
    #pragma unroll
    for (int nt=0; nt<4; ++nt) bfr[nt]=*(bf16x8*)(&hs[((ks*4+quad)*64 + nt*16 + l16)*8]);
    #pragma unroll
    for (int mt=0; mt<4; ++mt){
      bf16x8 afr = *(const bf16x8*)(&A.w2b[(m0+mt*16+l16)*128 + ks*32 + quad*8]);
      #pragma unroll
      for (int nt=0; nt<4; ++nt)
        acc[mt][nt]=__builtin_amdgcn_mfma_f32_16x16x32_bf16(afr, bfr[nt], acc[mt][nt], 0,0,0);
    }
  }
  bool uni = (segp[0]==segp[63]); int seg0=segp[0];
  size_t tb = (size_t)(blockIdx.x>>1)*32768;   // ntile base in fbufp entries
  int prelb = (blockIdx.x&1)*64;
  #pragma unroll
  for (int mt=0;mt<4;++mt){
    int cout0=m0+mt*16+quad*4;
    int kg=cout0>>3, sub=cout0&7;
    float fv[4][4];
    #pragma unroll
    for (int nt=0;nt<4;++nt)
      #pragma unroll
      for (int r=0;r<4;++r)
        fv[nt][r]=fmaf(a2s[cout0+r], acc[mt][nt][r], c2s[cout0+r]);
    #pragma unroll
    for (int nt=0;nt<4;++nt){
      int ptl=nt*16+l16;
      uint2 pk;
      pk.x=(unsigned)f2bf(fv[nt][0])|((unsigned)f2bf(fv[nt][1])<<16);
      pk.y=(unsigned)f2bf(fv[nt][2])|((unsigned)f2bf(fv[nt][3])<<16);
      *(uint2*)&A.fbufp[tb + (size_t)((kg*128 + prelb + ptl)*8 + sub)] = pk;
    }
    #pragma unroll
    for (int r=0;r<4;++r){
      if (uni){
        float mv=fmaxf(fmaxf(fv[0][r],fv[1][r]),fmaxf(fv[2][r],fv[3][r]));
        #pragma unroll
        for (int off=8;off>=1;off>>=1) mv=fmaxf(mv, __shfl_xor(mv,off));
        if (l16==0) atomicMax(&A.gkeys[seg0*256+cout0+r], f2key(mv));
      } else {
        #pragma unroll
        for (int nt=0;nt<4;++nt)
          atomicMax(&A.gkeys[segp[nt*16+l16]*256+cout0+r], f2key(fv[nt][r]));
      }
    }
  }
}

// ---------------- cseg[seg][cout] = W3[:, :256] @ gs(seg) ----------------
__global__ void k_cseg(Args A){
  int seg = blockIdx.x>>1; int cout = (blockIdx.x&1)*256 + threadIdx.x;
  __shared__ float gs[256];
  gs[threadIdx.x] = key2f(A.gkeys[seg*256+threadIdx.x]);
  __syncthreads();
  const float* wrow = A.W3 + (size_t)cout*512;
  float s=0.f;
  #pragma unroll 8
  for (int k=0;k<256;k++) s = fmaf(wrow[k], gs[k], s);
  A.cseg[seg*512+cout]=s;
}

// ---------------- L3: m97-structure 128x128 tile, BK=64, gl16 staging, 2-barrier loop ----------------
// 4096 blocks x 256 thr (4 waves). Block = 128 couts (mtile of 4) x 128 pts (ntile of 1024).
// 32 KB LDS -> 4 blocks/CU; XCD swizzle co-locates the 4 mtile-sharers of each ntile.
__global__ __launch_bounds__(256,4) void k_l3(Args A){
  __shared__ unsigned short sA[8192], sB[8192];   // [8 kgg][128][8] each, 16 KB each
  __shared__ int offs_s[NSEG+1];
  int bid=blockIdx.x, xcd=bid&7, idx=bid>>3;
  int mtile=idx&3, ntile=xcd*128+(idx>>2);
  int tid=threadIdx.x, lane=tid&63, wv=tid>>6, quad=lane>>4, l16=lane&15;
  int mq=wv&1, nq=wv>>1;
  const char* wbase=(const char*)A.w3p   + (size_t)mtile*65536;   // 4 ksteps x 16 KB
  const char* bbase=(const char*)A.fbufp + (size_t)ntile*65536;
  if (tid<=NSEG) offs_s[tid]=A.offs[tid];
  f32x4 acc[4][4];
  for (int a=0;a<4;a++)
    for (int b=0;b<4;b++)
      acc[a][b]=(f32x4){0.f,0.f,0.f,0.f};
  for (int s=0;s<4;++s){
    const char* srcA = wbase + s*16384;
    const char* srcB = bbase + s*16384;
    #pragma unroll
    for (int i=0;i<4;++i){
      gl16(srcA + wv*4096 + i*1024 + lane*16, (char*)sA + wv*4096 + i*1024);
      gl16(srcB + wv*4096 + i*1024 + lane*16, (char*)sB + wv*4096 + i*1024);
    }
    __syncthreads();
    #pragma unroll
    for (int ks=0;ks<2;++ks){
      bf16x8 bb[4], afr[4];
      #pragma unroll
      for (int nt=0;nt<4;++nt) bb[nt]=*(const bf16x8*)(&sB[((ks*4+quad)*128 + nq*64 + nt*16 + l16)*8]);
      #pragma unroll
      for (int mt=0;mt<4;++mt) afr[mt]=*(const bf16x8*)(&sA[((ks*4+quad)*128 + mq*64 + mt*16 + l16)*8]);
      #pragma unroll
      for (int mt=0;mt<4;++mt)
        #pragma unroll
        for (int nt=0;nt<4;++nt)
          acc[mt][nt]=__builtin_amdgcn_mfma_f32_16x16x32_bf16(afr[mt], bb[nt], acc[mt][nt], 0,0,0);
    }
    __syncthreads();
  }
  // epilogue: BN + ReLU + cseg add, pack to h3p
  int pt0 = ntile*128 + nq*64;
  int sBeg=0; while (pt0 >= offs_s[sBeg+1]) sBeg++;
  int sEnd=sBeg; while (pt0+63 >= offs_s[sEnd+1]) sEnd++;
  bool uni=(sBeg==sEnd);
  int segl[4];
  if (!uni){
    #pragma unroll
    for (int nt=0;nt<4;++nt){ int gp=pt0+nt*16+l16, ss=sBeg; while (gp>=offs_s[ss+1]) ss++; segl[nt]=ss; }
  }
  size_t hb = (size_t)ntile*65536;
  #pragma unroll
  for (int mt=0;mt<4;++mt){
    int cout0=mtile*128 + mq*64 + mt*16 + quad*4;
    int kg=cout0>>3, sub=cout0&7;
    float sa[4],sc[4],csr[4];
    #pragma unroll
    for (int r=0;r<4;++r){ sa[r]=A.a3[cout0+r]; sc[r]=A.c3[cout0+r]; }
    if (uni){
      #pragma unroll
      for (int r=0;r<4;++r) csr[r]=A.cseg[sBeg*512+cout0+r];
    }
    #pragma unroll
    for (int nt=0;nt<4;++nt){
      int prel=nq*64+nt*16+l16;
      unsigned short us[4];
      #pragma unroll
      for (int r=0;r<4;++r){
        float cv = uni? csr[r] : A.cseg[segl[nt]*512+cout0+r];
        float hv = fmaxf(fmaf(sa[r], acc[mt][nt][r]+cv, sc[r]), 0.f);
        us[r]=f2bf(hv);
      }
      uint2 pk;
      pk.x=(unsigned)us[0]|((unsigned)us[1]<<16);
      pk.y=(unsigned)us[2]|((unsigned)us[3]<<16);
      *(uint2*)&A.h3p[hb + (size_t)((kg*128+prel)*8+sub)] = pk;
    }
  }
}

// ---------------- L4: m97-structure, K=512 (8 ksteps), fused segmax ----------------
// 8192 blocks x 256 thr. Block = 128 couts (mtile of 8) x 128 pts (ntile of 1024).
__global__ __launch_bounds__(256,4) void k_l4(Args A){
  __shared__ unsigned short sA[8192], sB[8192];
  __shared__ int offs_s[NSEG+1];
  int bid=blockIdx.x, xcd=bid&7, idx=bid>>3;
  int mtile=idx&7, ntile=xcd*128+(idx>>3);
  int tid=threadIdx.x, lane=tid&63, wv=tid>>6, quad=lane>>4, l16=lane&15;
  int mq=wv&1, nq=wv>>1;
  const char* wbase=(const char*)A.w4p + (size_t)mtile*131072;   // 8 ksteps x 16 KB
  const char* bbase=(const char*)A.h3p + (size_t)ntile*131072;
  if (tid<=NSEG) offs_s[tid]=A.offs[tid];
  f32x4 acc[4][4];
  for (int a=0;a<4;a++)
    for (int b=0;b<4;b++)
      acc[a][b]=(f32x4){0.f,0.f,0.f,0.f};
  for (int s=0;s<8;++s){
    const char* srcA = wbase + s*16384;
    const char* srcB = bbase + s*16384;
    #pragma unroll
    for (int i=0;i<4;++i){
      gl16(srcA + wv*4096 + i*1024 + lane*16, (char*)sA + wv*4096 + i*1024);
      gl16(srcB + wv*4096 + i*1024 + lane*16, (char*)sB + wv*4096 + i*1024);
    }
    __syncthreads();
    #pragma unroll
    for (int ks=0;ks<2;++ks){
      bf16x8 bb[4], afr[4];
      #pragma unroll
      for (int nt=0;nt<4;++nt) bb[nt]=*(const bf16x8*)(&sB[((ks*4+quad)*128 + nq*64 + nt*16 + l16)*8]);
      #pragma unroll
      for (int mt=0;mt<4;++mt) afr[mt]=*(const bf16x8*)(&sA[((ks*4+quad)*128 + mq*64 + mt*16 + l16)*8]);
      #pragma unroll
      for (int mt=0;mt<4;++mt)
        #pragma unroll
        for (int nt=0;nt<4;++nt)
          acc[mt][nt]=__builtin_amdgcn_mfma_f32_16x16x32_bf16(afr[mt], bb[nt], acc[mt][nt], 0,0,0);
    }
    __syncthreads();
  }
  // epilogue: BN + fused segmax
  int pt0 = ntile*128 + nq*64;
  int sBeg=0; while (pt0 >= offs_s[sBeg+1]) sBeg++;
  int sEnd=sBeg; while (pt0+63 >= offs_s[sEnd+1]) sEnd++;
  bool uni=(sBeg==sEnd);
  int segl[4];
  if (!uni){
    #pragma unroll
    for (int nt=0;nt<4;++nt){ int gp=pt0+nt*16+l16, ss=sBeg; while (gp>=offs_s[ss+1]) ss++; segl[nt]=ss; }
  }
  #pragma unroll
  for (int mt=0;mt<4;++mt){
    int cout0=mtile*128 + mq*64 + mt*16 + quad*4;
    #pragma unroll
    for (int r=0;r<4;++r){
      int cout=cout0+r;
      float sa=A.a4[cout], sc=A.c4[cout];
      float mv=-3.4e38f;
      #pragma unroll
      for (int nt=0;nt<4;++nt){
        float fv=fmaf(sa, acc[mt][nt][r], sc);
        if (uni) mv=fmaxf(mv,fv);
        else atomicMax(&A.vkeys[segl[nt]*1024+cout], f2key(fv));
      }
      if (uni){
        #pragma unroll
        for (int off=8;off>=1;off>>=1) mv=fmaxf(mv, __shfl_xor(mv,off));
        if (l16==0) atomicMax(&A.vkeys[sBeg*1024+cout], f2key(mv));
      }
    }
  }
}

// ---------------- decode ----------------
__global__ void k_final(Args A){
  int i=blockIdx.x*256+threadIdx.x;
  if (i<NSEG*1024) A.out[i]=key2f(A.vkeys[i]);
}

extern "C" void kernel_launch(void* const* d_in, const int* in_sizes, int n_in,
                              void* d_out, int out_size, void* d_ws, size_t ws_size,
                              hipStream_t stream){
  Args A;
  A.x  =(const float*)d_in[0];  A.npts=(const int*)d_in[1];
  A.W1 =(const float*)d_in[2];  A.b1 =(const float*)d_in[3];
  A.g1 =(const float*)d_in[4];  A.be1=(const float*)d_in[5];
  A.m1 =(const float*)d_in[6];  A.v1 =(const float*)d_in[7];
  A.W2 =(const float*)d_in[8];  A.b2 =(const float*)d_in[9];
  A.g2 =(const float*)d_in[10]; A.be2=(const float*)d_in[11];
  A.m2 =(const float*)d_in[12]; A.v2 =(const float*)d_in[13];
  A.W3 =(const float*)d_in[14]; A.b3 =(const float*)d_in[15];
  A.g3 =(const float*)d_in[16]; A.be3=(const float*)d_in[17];
  A.m3 =(const float*)d_in[18]; A.v3 =(const float*)d_in[19];
  A.W4 =(const float*)d_in[20]; A.b4 =(const float*)d_in[21];
  A.g4 =(const float*)d_in[22]; A.be4=(const float*)d_in[23];
  A.m4 =(const float*)d_in[24]; A.v4 =(const float*)d_in[25];

  char* w=(char*)d_ws;
  auto alloc=[&](size_t b)->void*{ void* p=(void*)w; w += (b+255)&~(size_t)255; return p; };
  A.offs =(int*)alloc((NSEG+1)*4);
  A.a1=(float*)alloc(128*4);  A.c1=(float*)alloc(128*4);
  A.a2=(float*)alloc(256*4);  A.c2=(float*)alloc(256*4);
  A.a3=(float*)alloc(512*4);  A.c3=(float*)alloc(512*4);
  A.a4=(float*)alloc(1024*4); A.c4=(float*)alloc(1024*4);
  A.gkeys=(unsigned int*)alloc(NSEG*256*4);
  A.vkeys=(unsigned int*)alloc(NSEG*1024*4);
  A.cseg =(float*)alloc(NSEG*512*4);
  A.w2b=(unsigned short*)alloc(256*128*2);
  A.w3p=(unsigned short*)alloc(131072*2);
  A.w4p=(unsigned short*)alloc(524288*2);
  A.fbufp=(unsigned short*)alloc((size_t)1024*32768*2);  // 64 MB
  A.h3p  =(unsigned short*)alloc((size_t)1024*65536*2);  // 128 MB
  A.out=(float*)d_out;

  k_setup<<<dim3(1),dim3(256),0,stream>>>(A);
  k_conv <<<dim3(2688),dim3(256),0,stream>>>(A);
  k_l12  <<<dim3(NTOT/64),dim3(256),0,stream>>>(A);
  k_cseg <<<dim3(32),dim3(256),0,stream>>>(A);
  k_l3   <<<dim3(4096),dim3(256),0,stream>>>(A);
  k_l4   <<<dim3(8192),dim3(256),0,stream>>>(A);
  k_final<<<dim3(64),dim3(256),0,stream>>>(A);
}